// Round 3
// baseline (16030.208 us; speedup 1.0000x reference)
//
#include <hip/hip_runtime.h>

#define LOWV (-10000.0f)
#define NB 256
typedef unsigned long long u64;

__device__ __forceinline__ float sigf(float x){ return 1.0f/(1.0f+expf(-x)); }
__device__ __forceinline__ unsigned fkey(float f){
    unsigned u = __float_as_uint(f);
    return (u & 0x80000000u) ? ~u : (u | 0x80000000u);
}
__device__ __forceinline__ float funkey(unsigned k){
    unsigned u = (k & 0x80000000u) ? (k ^ 0x80000000u) : ~k;
    return __uint_as_float(u);
}

// ---------- tiled transposes: WhxT[2560][640], WpredT[512][640], WoutT[1024][512], WencT[512][1024]
__global__ __launch_bounds__(256) void k_tr(const float* __restrict__ Wh, const float* __restrict__ Wpred,
        const float* __restrict__ Wout, const float* __restrict__ Wenc,
        float* __restrict__ WhxT, float* __restrict__ WpredT, float* __restrict__ WoutT, float* __restrict__ WencT){
    __shared__ float t[64][65];
    int b = blockIdx.x;
    const float* in; float* outp; int R, C, tr, tc;
    if (b < 400){ in=Wh;   outp=WhxT;   R=640;  C=2560; tr=b/40; tc=b%40; }
    else if (b < 480){ b-=400; in=Wpred; outp=WpredT; R=640;  C=512;  tr=b/8;  tc=b%8; }
    else if (b < 608){ b-=480; in=Wout;  outp=WoutT;  R=512;  C=1024; tr=b/16; tc=b%16; }
    else       { b-=608; in=Wenc;  outp=WencT;  R=1024; C=512;  tr=b/8;  tc=b%8; }
    int tx = threadIdx.x & 63, ty0 = threadIdx.x >> 6;
    #pragma unroll
    for (int i = 0; i < 16; ++i){
        int row = i*4 + ty0;
        t[row][tx] = in[(size_t)(tr*64 + row)*C + tc*64 + tx];
    }
    __syncthreads();
    #pragma unroll
    for (int i = 0; i < 16; ++i){
        int row = i*4 + ty0;
        outp[(size_t)(tc*64 + row)*R + tr*64 + tx] = t[tx][row];
    }
}

// ---------- EWi4[v][j] = float4 gates (i,f,g,o) of E@Wi + bi + bh ----------
__global__ __launch_bounds__(256) void k_ewi(const float* __restrict__ E, const float* __restrict__ Wi,
        const float* __restrict__ bi, const float* __restrict__ bh,
        float4* __restrict__ EWi4, int* __restrict__ cnt){
    if (blockIdx.x == 0 && threadIdx.x == 0) *cnt = 0;
    int tid = threadIdx.x, lane = tid & 63, wvv = tid >> 6;
    int vb = blockIdx.x / 10, jb = blockIdx.x % 10;
    int j = jb*64 + lane;
    int v0 = vb*16 + wvv*4;
    float acc[4][4];
    #pragma unroll
    for (int i=0;i<4;++i)
        #pragma unroll
        for (int g=0;g<4;++g) acc[i][g] = 0.f;
    for (int k0 = 0; k0 < 512; k0 += 4){
        float ev[4][4];
        #pragma unroll
        for (int i=0;i<4;++i) *(float4*)ev[i] = *(const float4*)(E + (size_t)(v0+i)*512 + k0);
        #pragma unroll
        for (int kk=0;kk<4;++kk){
            const float* wr = Wi + (size_t)(k0+kk)*2560 + j;
            float w0 = wr[0], w1 = wr[640], w2 = wr[1280], w3 = wr[1920];
            #pragma unroll
            for (int i=0;i<4;++i){
                acc[i][0] += ev[i][kk]*w0; acc[i][1] += ev[i][kk]*w1;
                acc[i][2] += ev[i][kk]*w2; acc[i][3] += ev[i][kk]*w3;
            }
        }
    }
    float b0 = bi[j] + bh[j], b1 = bi[640+j] + bh[640+j];
    float b2 = bi[1280+j] + bh[1280+j], b3 = bi[1920+j] + bh[1920+j];
    #pragma unroll
    for (int i=0;i<4;++i)
        EWi4[(size_t)(v0+i)*640 + j] = make_float4(acc[i][0]+b0, acc[i][1]+b1, acc[i][2]+b2, acc[i][3]+b3);
}

// ---------- persistent decode kernel ----------
__global__ __launch_bounds__(512) void mega(
    const float* __restrict__ enc, const int* __restrict__ lens, const float* __restrict__ bj,
    const float* __restrict__ WpredT, const float* __restrict__ WoutT,
    const float* __restrict__ WhxT, const float* __restrict__ WencT,
    const float4* __restrict__ EWi4,
    float* __restrict__ hT, float* __restrict__ cT, float* __restrict__ encPT,
    float* __restrict__ jointT, u64* __restrict__ packed, float* __restrict__ sumexp,
    int* __restrict__ actA, int* __restrict__ encTA, int* __restrict__ nEmA,
    float* __restrict__ scoresA, int* __restrict__ cnt, float* __restrict__ out)
{
    __shared__ float smem[15616];
    float* sA = smem;            // WpredT slice [2][640]
    float* sB = smem + 1280;     // WoutT slice  [4][512]
    float* sR = smem + 3328;     // role: D [16][640] | E [8][1024]
    float* sX = smem + 13568;    // 2048-float exchange
    const int bid = blockIdx.x, tid = threadIdx.x, lane = tid & 63, wv = tid >> 6;
    int ep = 0;

    auto gsync = [&](){
        __threadfence();
        __syncthreads();
        if (tid == 0){
            __hip_atomic_fetch_add(cnt, 1, __ATOMIC_ACQ_REL, __HIP_MEMORY_SCOPE_AGENT);
            ++ep;
            while (__hip_atomic_load(cnt, __ATOMIC_ACQUIRE, __HIP_MEMORY_SCOPE_AGENT) < ep*NB)
                __builtin_amdgcn_s_sleep(4);
        }
        __syncthreads();
    };

    // ---- persistent weight slices into LDS ----
    for (int i = tid; i < 1280; i += 512) sA[i] = WpredT[(size_t)bid*1280 + i];
    for (int i = tid; i < 2048; i += 512) sB[i] = WoutT[(size_t)bid*2048 + i];
    if (bid < 160){
        int j0 = bid*4;
        for (int i = tid; i < 10240; i += 512){
            int u = i / 640, k = i - u*640;         // u = g*4 + jj
            int g = u >> 2, jj = u & 3;
            sR[i] = WhxT[(size_t)(g*640 + j0 + jj)*640 + k];
        }
    } else if (bid < 224){
        int c0 = (bid-160)*8;
        for (int i = tid; i < 8192; i += 512) sR[i] = WencT[(size_t)c0*1024 + i];
    }
    __syncthreads();

    // ---- prologue: h0/c0, frame-0 encPT, zero atomics, scalar state ----
    if (bid < 160){
        int j0 = bid*4;
        int jj = tid >> 7, r = tid & 127;
        float4 e0 = EWi4[(size_t)(j0 + jj)];         // token OB=0 row
        float c0v = sigf(e0.x)*tanhf(e0.z);
        float h0v = tanhf(c0v)*sigf(e0.w);
        hT[(size_t)(j0+jj)*128 + r] = h0v;
        cT[(size_t)(j0+jj)*128 + r] = c0v;
    } else if (bid < 224){
        int cg0 = (bid-160)*8;
        int cc = wv;
        for (int r = 0; r < 128; ++r){
            const float* epr = enc + (size_t)r*160*1024;   // frame 0
            float acc = 0.f;
            #pragma unroll
            for (int c16 = 0; c16 < 16; ++c16){
                int k = c16*64 + lane;
                acc += epr[k] * sR[cc*1024 + k];
            }
            #pragma unroll
            for (int off = 32; off; off >>= 1) acc += __shfl_xor(acc, off, 64);
            if (lane == 0) encPT[(size_t)(cg0+cc)*128 + r] = acc;
        }
    } else if (bid == 224){
        for (int i = tid; i < 6144; i += 512){ packed[i] = 0ull; sumexp[i] = 0.f; }
        if (tid < 128){ actA[tid] = 1; encTA[tid] = 0; nEmA[tid] = 0; scoresA[tid] = 0.f; }
    }
    gsync();

    for (int s = 0; s < 48; ++s){
        const int p = s & 1, w = 1 - p;
        const float* hp = hT + (size_t)p*81920;
        // ---------- phase A: jointT = tanh(encPT + Wpred^T h + bj) ----------
        {
            int c = wv & 1, rh = (wv >> 1) & 1, kh = wv >> 2;
            int r = rh*64 + lane;
            const float* wr = sA + c*640;
            const float* hcol = hp + r;
            float acc = 0.f;
            #pragma unroll 4
            for (int k = kh*320; k < kh*320 + 320; ++k)
                acc += hcol[(size_t)k*128] * wr[k];
            sX[wv*64 + lane] = acc;
            __syncthreads();
            if (wv < 4){
                int c2 = wv & 1, rh2 = wv >> 1;
                int r2 = rh2*64 + lane;
                int cg = bid*2 + c2;
                float v = sX[(c2 + rh2*2)*64 + lane] + sX[(c2 + rh2*2 + 4)*64 + lane]
                        + encPT[(size_t)cg*128 + r2] + bj[cg];
                jointT[(size_t)cg*128 + r2] = tanhf(v);
            }
        }
        gsync();
        // ---------- phase B: logits, per-row argmax-key + sumexp via atomics ----------
        {
            int cw = wv & 3, rh = wv >> 2;
            int r = rh*64 + lane;
            int c = bid*4 + cw;
            const float* wr = sB + cw*512;
            const float* jcol = jointT + r;
            float acc = 0.f;
            #pragma unroll 8
            for (int k = 0; k < 512; ++k)
                acc += jcol[(size_t)k*128] * wr[k];
            float ex = expf(acc);
            bool force = nEmA[p*128 + r] >= 2;
            int idx; float va;
            if (c == 0){ idx = 1024; va = acc; }            // appended blank col
            else { idx = c; va = force ? LOWV : acc; }
            u64 key = ((u64)fkey(va) << 32) | (unsigned)(2047 - idx);
            u64* kx = (u64*)sX;
            float* exf = (float*)(kx + 512);
            kx[cw*128 + r] = key;
            exf[cw*128 + r] = ex;
            __syncthreads();
            if (tid < 128){
                u64* kx2 = (u64*)sX;
                float* exf2 = (float*)(kx2 + 512);
                u64 m = kx2[tid]; float es = exf2[tid];
                #pragma unroll
                for (int q = 1; q < 4; ++q){
                    u64 o = kx2[q*128 + tid]; if (o > m) m = o;
                    es += exf2[q*128 + tid];
                }
                atomicMax(&packed[(size_t)s*128 + tid], m);
                atomicAdd(&sumexp[(size_t)s*128 + tid], es);
            }
        }
        gsync();
        // ---------- phase C/D/E ----------
        if (bid < 160){
            // D: LSTM for j-cols j0..j0+3
            int j0 = bid*4;
            int r2 = tid & 127, jj2 = tid >> 7;
            u64 pk2 = packed[(size_t)s*128 + r2];
            int tok2 = 2047 - (int)(unsigned)(pk2 & 0xffffffffu);
            int tokc = tok2 < 1023 ? tok2 : 1023;
            float4 ew4 = EWi4[(size_t)tokc*640 + j0 + jj2];   // prefetch, hides gather latency
            int act2 = actA[p*128 + r2];
            int rh = wv >> 2, u0 = (wv & 3)*4;
            int r = rh*64 + lane;
            const float* hcol = hp + r;
            const float* w0 = sR + (u0+0)*640;
            const float* w1 = sR + (u0+1)*640;
            const float* w2 = sR + (u0+2)*640;
            const float* w3 = sR + (u0+3)*640;
            float a0=0.f, a1=0.f, a2=0.f, a3=0.f;
            #pragma unroll 4
            for (int k = 0; k < 640; ++k){
                float h = hcol[(size_t)k*128];
                a0 += h*w0[k]; a1 += h*w1[k]; a2 += h*w2[k]; a3 += h*w3[k];
            }
            sX[(u0+0)*128 + r] = a0;
            sX[(u0+1)*128 + r] = a1;
            sX[(u0+2)*128 + r] = a2;
            sX[(u0+3)*128 + r] = a3;
            __syncthreads();
            bool upd = act2 && (tok2 != 1024);
            float gi = sX[(0  + jj2)*128 + r2] + ew4.x;
            float gf = sX[(4  + jj2)*128 + r2] + ew4.y;
            float gg = sX[(8  + jj2)*128 + r2] + ew4.z;
            float go = sX[(12 + jj2)*128 + r2] + ew4.w;
            int j = j0 + jj2;
            float hnew;
            if (upd){
                float cold = cT[(size_t)j*128 + r2];
                float c2v = sigf(gf)*cold + sigf(gi)*tanhf(gg);
                hnew = tanhf(c2v)*sigf(go);
                cT[(size_t)j*128 + r2] = c2v;
            } else {
                hnew = hp[(size_t)j*128 + r2];
            }
            hT[(size_t)w*81920 + (size_t)j*128 + r2] = hnew;
        } else if (bid < 224){
            // E: enc projection for rows that consumed a blank
            int cg0 = (bid-160)*8;
            int cc = wv;
            #pragma unroll
            for (int half = 0; half < 2; ++half){
                int r = half*64 + lane;
                u64 pk = packed[(size_t)s*128 + r];
                int tok = 2047 - (int)(unsigned)(pk & 0xffffffffu);
                bool blank = actA[p*128 + r] && (tok == 1024);
                u64 m = __ballot(blank);
                while (m){
                    int b = __ffsll((long long)m) - 1; m &= m - 1;
                    int rr = half*64 + b;
                    int t = encTA[p*128 + rr] + 1; if (t > 159) t = 159;
                    const float* epr = enc + ((size_t)rr*160 + t)*1024;
                    float acc = 0.f;
                    #pragma unroll
                    for (int c16 = 0; c16 < 16; ++c16){
                        int k = c16*64 + lane;
                        acc += epr[k]*sR[cc*1024 + k];
                    }
                    #pragma unroll
                    for (int off = 32; off; off >>= 1) acc += __shfl_xor(acc, off, 64);
                    if (lane == 0) encPT[(size_t)(cg0+cc)*128 + rr] = acc;
                }
            }
        } else if (bid == 224){
            // C: scalar state machine
            if (tid < 128){
                int r = tid;
                int act = actA[p*128 + r];
                int et  = encTA[p*128 + r];
                int ne  = nEmA[p*128 + r];
                float sc = scoresA[p*128 + r];
                int len = lens[r];
                int tok_out = 1024, act_n = 0;
                if (act){
                    u64 pk = packed[(size_t)s*128 + r];
                    int tok = 2047 - (int)(unsigned)(pk & 0xffffffffu);
                    float chosen = funkey((unsigned)(pk >> 32));
                    float tlp = chosen - logf(sumexp[(size_t)s*128 + r]);
                    int isb = (tok == 1024);
                    sc += tlp;
                    et += isb ? 1 : 0;
                    ne  = isb ? 0 : ne + 1;
                    act_n = (et < len) ? 1 : 0;
                    tok_out = (act_n || isb) ? tok : 1024;
                }
                actA[w*128 + r] = act_n;
                encTA[w*128 + r] = et;
                nEmA[w*128 + r] = ne;
                scoresA[w*128 + r] = sc;
                out[(size_t)r*48 + s] = (float)tok_out;
                if (s == 47) out[6144 + r] = sc;
            }
        }
        gsync();
    }
}

extern "C" void kernel_launch(void* const* d_in, const int* in_sizes, int n_in,
                              void* d_out, int out_size, void* d_ws, size_t ws_size,
                              hipStream_t stream) {
    const float* enc   = (const float*)d_in[0];
    const int*   lens  = (const int*)  d_in[1];
    const float* E     = (const float*)d_in[3];
    const float* Wi    = (const float*)d_in[4];
    const float* Wh    = (const float*)d_in[5];
    const float* bi    = (const float*)d_in[6];
    const float* bh    = (const float*)d_in[7];
    const float* Wenc  = (const float*)d_in[8];
    const float* Wpred = (const float*)d_in[9];
    const float* bj    = (const float*)d_in[10];
    const float* Wout  = (const float*)d_in[11];
    float* out = (float*)d_out;

    char* base = (char*)d_ws;
    size_t off = 0;
    auto carve = [&](size_t bytes) -> void* {
        void* pp = base + off;
        off += (bytes + 255) & ~(size_t)255;
        return pp;
    };
    float* WhxT  = (float*)carve((size_t)2560*640*4);
    float* WpredT= (float*)carve((size_t)512*640*4);
    float* WoutT = (float*)carve((size_t)1024*512*4);
    float* WencT = (float*)carve((size_t)512*1024*4);
    float4* EWi4 = (float4*)carve((size_t)1024*640*16);
    float* hT    = (float*)carve((size_t)2*640*128*4);
    float* cT    = (float*)carve((size_t)640*128*4);
    float* encPT = (float*)carve((size_t)512*128*4);
    float* jointT= (float*)carve((size_t)512*128*4);
    u64*   packed= (u64*)carve((size_t)48*128*8);
    float* sumexp= (float*)carve((size_t)48*128*4);
    int*   actA  = (int*)carve(2*128*4);
    int*   encTA = (int*)carve(2*128*4);
    int*   nEmA  = (int*)carve(2*128*4);
    float* scoresA = (float*)carve(2*128*4);
    int*   cnt   = (int*)carve(256);
    (void)ws_size; (void)in_sizes; (void)n_in; (void)out_size;

    k_tr <<<736, 256, 0, stream>>>(Wh, Wpred, Wout, Wenc, WhxT, WpredT, WoutT, WencT);
    k_ewi<<<640, 256, 0, stream>>>(E, Wi, bi, bh, EWi4, cnt);
    mega <<<NB, 512, 0, stream>>>(enc, lens, bj, WpredT, WoutT, WhxT, WencT, EWi4,
                                  hT, cT, encPT, jointT, packed, sumexp,
                                  actA, encTA, nEmA, scoresA, cnt, out);
}

// Round 4
// 5091.660 us; speedup vs baseline: 3.1483x; 3.1483x over previous
//
#include <hip/hip_runtime.h>

#define LOWV (-10000.0f)
#define NBLK 256
typedef unsigned long long u64;

__device__ __forceinline__ float sigf(float x){ return 1.0f/(1.0f+expf(-x)); }
__device__ __forceinline__ unsigned fkey(float f){
    unsigned u = __float_as_uint(f);
    return (u & 0x80000000u) ? ~u : (u | 0x80000000u);
}
__device__ __forceinline__ float funkey(unsigned k){
    unsigned u = (k & 0x80000000u) ? (k ^ 0x80000000u) : ~k;
    return __uint_as_float(u);
}

// ---------- tiled transposes: WhxT[2560][640], WpredT[512][640], WoutT[1024][512], WencT[512][1024]
__global__ __launch_bounds__(256) void k_tr(const float* __restrict__ Wh, const float* __restrict__ Wpred,
        const float* __restrict__ Wout, const float* __restrict__ Wenc,
        float* __restrict__ WhxT, float* __restrict__ WpredT, float* __restrict__ WoutT, float* __restrict__ WencT){
    __shared__ float t[64][65];
    int b = blockIdx.x;
    const float* in; float* outp; int R, C, tr, tc;
    if (b < 400){ in=Wh;   outp=WhxT;   R=640;  C=2560; tr=b/40; tc=b%40; }
    else if (b < 480){ b-=400; in=Wpred; outp=WpredT; R=640;  C=512;  tr=b/8;  tc=b%8; }
    else if (b < 608){ b-=480; in=Wout;  outp=WoutT;  R=512;  C=1024; tr=b/16; tc=b%16; }
    else       { b-=608; in=Wenc;  outp=WencT;  R=1024; C=512;  tr=b/8;  tc=b%8; }
    int tx = threadIdx.x & 63, ty0 = threadIdx.x >> 6;
    #pragma unroll
    for (int i = 0; i < 16; ++i){
        int row = i*4 + ty0;
        t[row][tx] = in[(size_t)(tr*64 + row)*C + tc*64 + tx];
    }
    __syncthreads();
    #pragma unroll
    for (int i = 0; i < 16; ++i){
        int row = i*4 + ty0;
        outp[(size_t)(tc*64 + row)*R + tr*64 + tx] = t[tx][row];
    }
}

// ---------- EWi4[v][j] = float4 gates (i,f,g,o) of E@Wi + bi + bh ----------
__global__ __launch_bounds__(256) void k_ewi(const float* __restrict__ E, const float* __restrict__ Wi,
        const float* __restrict__ bi, const float* __restrict__ bh,
        float4* __restrict__ EWi4, int* __restrict__ cnt8){
    if (blockIdx.x == 0 && threadIdx.x < 8) cnt8[threadIdx.x*16] = 0;
    int tid = threadIdx.x, lane = tid & 63, wvv = tid >> 6;
    int vb = blockIdx.x / 10, jb = blockIdx.x % 10;
    int j = jb*64 + lane;
    int v0 = vb*16 + wvv*4;
    float acc[4][4];
    #pragma unroll
    for (int i=0;i<4;++i)
        #pragma unroll
        for (int g=0;g<4;++g) acc[i][g] = 0.f;
    for (int k0 = 0; k0 < 512; k0 += 4){
        float ev[4][4];
        #pragma unroll
        for (int i=0;i<4;++i) *(float4*)ev[i] = *(const float4*)(E + (size_t)(v0+i)*512 + k0);
        #pragma unroll
        for (int kk=0;kk<4;++kk){
            const float* wr = Wi + (size_t)(k0+kk)*2560 + j;
            float w0 = wr[0], w1 = wr[640], w2 = wr[1280], w3 = wr[1920];
            #pragma unroll
            for (int i=0;i<4;++i){
                acc[i][0] += ev[i][kk]*w0; acc[i][1] += ev[i][kk]*w1;
                acc[i][2] += ev[i][kk]*w2; acc[i][3] += ev[i][kk]*w3;
            }
        }
    }
    float b0 = bi[j] + bh[j], b1 = bi[640+j] + bh[640+j];
    float b2 = bi[1280+j] + bh[1280+j], b3 = bi[1920+j] + bh[1920+j];
    #pragma unroll
    for (int i=0;i<4;++i)
        EWi4[(size_t)(v0+i)*640 + j] = make_float4(acc[i][0]+b0, acc[i][1]+b1, acc[i][2]+b2, acc[i][3]+b3);
}

// ---------- persistent decode kernel ----------
__global__ __launch_bounds__(512) void mega(
    const float* __restrict__ enc, const int* __restrict__ lens, const float* __restrict__ bj,
    const float* __restrict__ WpredT, const float* __restrict__ WoutT,
    const float* __restrict__ WhxT, const float* __restrict__ WencT,
    const float4* __restrict__ EWi4,
    float* __restrict__ hT, float* __restrict__ encPT, float* __restrict__ jointT,
    u64* __restrict__ packed, float* __restrict__ sumexp,
    int* __restrict__ actA, int* __restrict__ encTA, int* __restrict__ nEmA,
    float* __restrict__ scoresA, int* __restrict__ cnt8, float* __restrict__ out)
{
    __shared__ float sA[1280];      // WpredT 2 cols
    __shared__ float sWe[2048];     // WencT 2 cols
    __shared__ float sB[2048];      // WoutT 4 cols
    __shared__ float sR[10240];     // Whx slice 16 gate-cols (blocks<160)
    __shared__ float sXD[2048];     // Dpre gates [16][128]
    __shared__ float sXA[512];      // A partials
    __shared__ u64   sKX[512];      // B keys
    __shared__ float sEX[512];      // B exps
    __shared__ float sBJ[2];

    const int bid = blockIdx.x, tid = threadIdx.x, lane = tid & 63, wv = tid >> 6;
    const int j0 = bid*4;           // LSTM pred-cols for D-blocks
    int ep = 0;
    float creg = 0.f;

    auto gsync = [&](bool inv){
        __syncthreads();
        if (tid == 0){
            __builtin_amdgcn_fence(__ATOMIC_RELEASE, "agent");
            __hip_atomic_fetch_add(&cnt8[(bid & 7)*16], 1, __ATOMIC_RELAXED, __HIP_MEMORY_SCOPE_AGENT);
            ++ep;
            for (;;){
                int sum = 0;
                #pragma unroll
                for (int i = 0; i < 8; ++i)
                    sum += __hip_atomic_load(&cnt8[i*16], __ATOMIC_RELAXED, __HIP_MEMORY_SCOPE_AGENT);
                if (sum >= ep*NBLK) break;
                __builtin_amdgcn_s_sleep(8);
            }
        }
        __syncthreads();
        if (inv) __builtin_amdgcn_fence(__ATOMIC_ACQUIRE, "agent");
    };

    // ---- persistent weight slices into LDS ----
    for (int i = tid; i < 1280; i += 512) sA[i] = WpredT[(size_t)bid*1280 + i];
    for (int i = tid; i < 2048; i += 512) sWe[i] = WencT[(size_t)bid*2048 + i];
    for (int i = tid; i < 2048; i += 512) sB[i] = WoutT[(size_t)bid*2048 + i];
    if (bid < 160){
        for (int i = tid; i < 10240; i += 512){
            int u = i / 640, k = i - u*640;
            int g = u >> 2, jj = u & 3;
            sR[i] = WhxT[(size_t)(g*640 + j0 + jj)*640 + k];
        }
    }
    if (tid < 2) sBJ[tid] = bj[bid*2 + tid];

    // ---- prologue state ----
    if (bid < 160){
        int r2 = tid & 127, jj2 = tid >> 7;
        float4 e0 = EWi4[j0 + jj2];
        float c0v = sigf(e0.x)*tanhf(e0.z);
        creg = c0v;
        float h0v = tanhf(c0v)*sigf(e0.w);
        hT[(size_t)(j0+jj2)*128 + r2] = h0v;     // parity slot 0
    }
    if (bid == 255){
        for (int i = tid; i < 6144; i += 512){ packed[i] = 0ull; sumexp[i] = 0.f; }
        if (tid < 128){ actA[tid] = 1; encTA[tid] = 0; nEmA[tid] = 0; scoresA[tid] = 0.f; }
    }
    gsync(true);

    for (int s = 0; s < 48; ++s){
        const int p = s & 1, w = 1 - p;
        const float* hp = hT + (size_t)p*81920;
        // ================= P1: encP lazy update + joint partials + LSTM pre-gates =================
        {
            const int* etc = encTA + p*128;
            const int* eto = encTA + w*128;
            for (int r = wv; r < 128; r += 8){
                int et = etc[r];
                bool redo = (s == 0) || (et != eto[r]);
                if (redo){
                    int t = et < 159 ? et : 159;
                    const float* er = enc + ((size_t)r*160 + t)*1024;
                    float a0 = 0.f, a1 = 0.f;
                    #pragma unroll
                    for (int i = 0; i < 4; ++i){
                        int k0 = i*256 + lane*4;
                        float4 ev = *(const float4*)(er + k0);
                        float4 wa = *(const float4*)(sWe + k0);
                        float4 wb = *(const float4*)(sWe + 1024 + k0);
                        a0 += ev.x*wa.x + ev.y*wa.y + ev.z*wa.z + ev.w*wa.w;
                        a1 += ev.x*wb.x + ev.y*wb.y + ev.z*wb.z + ev.w*wb.w;
                    }
                    #pragma unroll
                    for (int off = 32; off; off >>= 1){
                        a0 += __shfl_xor(a0, off, 64);
                        a1 += __shfl_xor(a1, off, 64);
                    }
                    if (lane == 0){
                        encPT[(size_t)(2*bid)*128 + r]   = a0;
                        encPT[(size_t)(2*bid+1)*128 + r] = a1;
                    }
                }
            }
        }
        {   // joint partials
            int c = wv & 1, rh = (wv >> 1) & 1, kh = wv >> 2;
            int r = rh*64 + lane;
            const float* wr = sA + c*640 + kh*320;
            const float* hc = hp + (size_t)(kh*320)*128 + r;
            float acc = 0.f;
            #pragma unroll 8
            for (int k = 0; k < 320; ++k) acc += hc[(size_t)k*128] * wr[k];
            sXA[wv*64 + lane] = acc;
        }
        if (bid < 160){  // LSTM pre-gates (speculative)
            int rh = wv >> 2, u0 = (wv & 3)*4;
            int r = rh*64 + lane;
            const float* hc = hp + r;
            const float* w0 = sR + (u0+0)*640;
            const float* w1 = sR + (u0+1)*640;
            const float* w2 = sR + (u0+2)*640;
            const float* w3 = sR + (u0+3)*640;
            float a0=0.f, a1=0.f, a2=0.f, a3=0.f;
            #pragma unroll 4
            for (int k = 0; k < 640; ++k){
                float h = hc[(size_t)k*128];
                a0 += h*w0[k]; a1 += h*w1[k]; a2 += h*w2[k]; a3 += h*w3[k];
            }
            sXD[(u0+0)*128 + r] = a0;
            sXD[(u0+1)*128 + r] = a1;
            sXD[(u0+2)*128 + r] = a2;
            sXD[(u0+3)*128 + r] = a3;
        }
        __syncthreads();
        if (tid < 256){  // joint finalize
            int c2 = wv & 1, rh2 = wv >> 1;
            int r2 = rh2*64 + lane;
            int cg = bid*2 + c2;
            float v = sXA[(c2 + rh2*2)*64 + lane] + sXA[(c2 + rh2*2 + 4)*64 + lane]
                    + encPT[(size_t)cg*128 + r2] + sBJ[c2];
            jointT[(size_t)cg*128 + r2] = tanhf(v);
        }
        gsync(false);
        // ================= P2: logits + argmax/sumexp atomics =================
        {
            int cw = wv & 3, rh = wv >> 2;
            int r = rh*64 + lane;
            int c = bid*4 + cw;
            int force = nEmA[p*128 + r] >= 2;
            const float* wr = sB + cw*512;
            const float* jc = jointT + r;
            float acc = 0.f;
            #pragma unroll 8
            for (int k = 0; k < 512; ++k) acc += jc[(size_t)k*128] * wr[k];
            float ex = expf(acc);
            int idx; float va;
            if (c == 0){ idx = 1024; va = acc; }
            else { idx = c; va = force ? LOWV : acc; }
            u64 key = ((u64)fkey(va) << 32) | (unsigned)(2047 - idx);
            sKX[cw*128 + r] = key;
            sEX[cw*128 + r] = ex;
            __syncthreads();
            if (tid < 128){
                u64 m = sKX[tid]; float es = sEX[tid];
                #pragma unroll
                for (int q = 1; q < 4; ++q){
                    u64 o = sKX[q*128 + tid]; if (o > m) m = o;
                    es += sEX[q*128 + tid];
                }
                atomicMax(&packed[(size_t)s*128 + tid], m);
                atomicAdd(&sumexp[(size_t)s*128 + tid], es);
            }
        }
        gsync(false);
        // ================= P3: LSTM finalize | scalar state =================
        if (bid < 160){
            int r2 = tid & 127, jj2 = tid >> 7;
            u64 pk = __hip_atomic_load(&packed[(size_t)s*128 + r2], __ATOMIC_RELAXED, __HIP_MEMORY_SCOPE_AGENT);
            int tok = 2047 - (int)(unsigned)(pk & 0xffffffffu);
            int act = actA[p*128 + r2];
            bool upd = act && (tok != 1024);
            int tokc = tok < 1023 ? tok : 1023;
            float4 ew = EWi4[(size_t)tokc*640 + j0 + jj2];
            int j = j0 + jj2;
            float h2;
            if (upd){
                float gi = sXD[(0  + jj2)*128 + r2] + ew.x;
                float gf = sXD[(4  + jj2)*128 + r2] + ew.y;
                float gg = sXD[(8  + jj2)*128 + r2] + ew.z;
                float go = sXD[(12 + jj2)*128 + r2] + ew.w;
                float cn = sigf(gf)*creg + sigf(gi)*tanhf(gg);
                h2 = tanhf(cn)*sigf(go);
                creg = cn;
            } else {
                h2 = hp[(size_t)j*128 + r2];
            }
            hT[(size_t)w*81920 + (size_t)j*128 + r2] = h2;
        } else if (bid == 255){
            if (tid < 128){
                int r = tid;
                int act = actA[p*128 + r];
                int et  = encTA[p*128 + r];
                int ne  = nEmA[p*128 + r];
                float sc = scoresA[p*128 + r];
                int len = lens[r];
                int tok_out = 1024, act_n = 0;
                if (act){
                    u64 pk = __hip_atomic_load(&packed[(size_t)s*128 + r], __ATOMIC_RELAXED, __HIP_MEMORY_SCOPE_AGENT);
                    int tok = 2047 - (int)(unsigned)(pk & 0xffffffffu);
                    float chosen = funkey((unsigned)(pk >> 32));
                    float se = __hip_atomic_load(&sumexp[(size_t)s*128 + r], __ATOMIC_RELAXED, __HIP_MEMORY_SCOPE_AGENT);
                    float tlp = chosen - logf(se);
                    int isb = (tok == 1024);
                    sc += tlp;
                    et += isb ? 1 : 0;
                    ne  = isb ? 0 : ne + 1;
                    act_n = (et < len) ? 1 : 0;
                    tok_out = (act_n || isb) ? tok : 1024;
                }
                actA[w*128 + r] = act_n;
                encTA[w*128 + r] = et;
                nEmA[w*128 + r] = ne;
                scoresA[w*128 + r] = sc;
                out[(size_t)r*48 + s] = (float)tok_out;
                if (s == 47) out[6144 + r] = sc;
            }
        }
        gsync(true);
    }
}

extern "C" void kernel_launch(void* const* d_in, const int* in_sizes, int n_in,
                              void* d_out, int out_size, void* d_ws, size_t ws_size,
                              hipStream_t stream) {
    const float* enc   = (const float*)d_in[0];
    const int*   lens  = (const int*)  d_in[1];
    const float* E     = (const float*)d_in[3];
    const float* Wi    = (const float*)d_in[4];
    const float* Wh    = (const float*)d_in[5];
    const float* bi    = (const float*)d_in[6];
    const float* bh    = (const float*)d_in[7];
    const float* Wenc  = (const float*)d_in[8];
    const float* Wpred = (const float*)d_in[9];
    const float* bj    = (const float*)d_in[10];
    const float* Wout  = (const float*)d_in[11];
    float* out = (float*)d_out;

    char* base = (char*)d_ws;
    size_t off = 0;
    auto carve = [&](size_t bytes) -> void* {
        void* pp = base + off;
        off += (bytes + 255) & ~(size_t)255;
        return pp;
    };
    float*  WhxT  = (float*)carve((size_t)2560*640*4);
    float*  WpredT= (float*)carve((size_t)512*640*4);
    float*  WoutT = (float*)carve((size_t)1024*512*4);
    float*  WencT = (float*)carve((size_t)512*1024*4);
    float4* EWi4  = (float4*)carve((size_t)1024*640*16);
    float*  hT    = (float*)carve((size_t)2*640*128*4);
    float*  encPT = (float*)carve((size_t)512*128*4);
    float*  jointT= (float*)carve((size_t)512*128*4);
    u64*    packed= (u64*)carve((size_t)48*128*8);
    float*  sumexp= (float*)carve((size_t)48*128*4);
    int*    actA  = (int*)carve(2*128*4);
    int*    encTA = (int*)carve(2*128*4);
    int*    nEmA  = (int*)carve(2*128*4);
    float*  scoresA = (float*)carve(2*128*4);
    int*    cnt8  = (int*)carve(8*16*4);
    (void)ws_size; (void)in_sizes; (void)n_in; (void)out_size;

    k_tr <<<736, 256, 0, stream>>>(Wh, Wpred, Wout, Wenc, WhxT, WpredT, WoutT, WencT);
    k_ewi<<<640, 256, 0, stream>>>(E, Wi, bi, bh, EWi4, cnt8);
    mega <<<NBLK, 512, 0, stream>>>(enc, lens, bj, WpredT, WoutT, WhxT, WencT, EWi4,
                                    hT, encPT, jointT, packed, sumexp,
                                    actA, encTA, nEmA, scoresA, cnt8, out);
}